// Round 1
// baseline (1492.526 us; speedup 1.0000x reference)
//
#include <hip/hip_runtime.h>
#include <hip/hip_bf16.h>

#define BIGF 3.402823466e38f
#define LCAP 2048u

// ---------------------------------------------------------------------------
// Workspace state. Harness poisons ws with 0xAA before each timed call, so
// k0_init re-initializes everything each launch.
// ---------------------------------------------------------------------------
struct State {
  double sum0, sumsq0;
  double sum1, sumsq1;
  double sum2, sumsq2;
  unsigned n0, n1, n2;
  float maxabs0, minnz0, maxnz0;
  float maxabs1, minnz1, maxnz1;
  float maxabs2, minnz2, maxnz2;
  float bmin0, bmax0;   // iter-0 inlier min/max (|x| <= thr0, zeros included naturally)
  float bmin1, bmax1;   // iter-1 band min/max (thr0 < |x| <= thr1)
  unsigned count1, count2;
  float thr[10], delta[10], zp[10];
  int valid[10];
};

// ---------------------------------------------------------------------------
// Atomic float min/max via CAS (few thousand ops total — contention-free).
// ---------------------------------------------------------------------------
__device__ inline void atomicMinF(float* addr, float v) {
  unsigned* ua = (unsigned*)addr;
  unsigned cur = *ua;
  while (v < __uint_as_float(cur)) {
    unsigned prev = atomicCAS(ua, cur, __float_as_uint(v));
    if (prev == cur) break;
    cur = prev;
  }
}
__device__ inline void atomicMaxF(float* addr, float v) {
  unsigned* ua = (unsigned*)addr;
  unsigned cur = *ua;
  while (v > __uint_as_float(cur)) {
    unsigned prev = atomicCAS(ua, cur, __float_as_uint(v));
    if (prev == cur) break;
    cur = prev;
  }
}

// ---------------------------------------------------------------------------
// 8-quantity accumulator: mask-stats (cnt,sum,sumsq,maxabs,minnz,maxnz) +
// band/inlier min/max (bmin,bmax).
// ---------------------------------------------------------------------------
struct Acc8 {
  double sum, sumsq;
  unsigned cnt;
  float maxabs, minnz, maxnz, bmin, bmax;
};
__device__ inline void acc_init(Acc8& a) {
  a.sum = 0.0; a.sumsq = 0.0; a.cnt = 0u;
  a.maxabs = 0.0f;            // reference maxabs = max(|xc|) over ALL elems incl zeros -> init 0 matches
  a.minnz = BIGF; a.maxnz = -BIGF;
  a.bmin = BIGF; a.bmax = -BIGF;
}
__device__ inline void acc_merge(Acc8& a, const Acc8& b) {
  a.sum += b.sum; a.sumsq += b.sumsq; a.cnt += b.cnt;
  a.maxabs = fmaxf(a.maxabs, b.maxabs);
  a.minnz = fminf(a.minnz, b.minnz); a.maxnz = fmaxf(a.maxnz, b.maxnz);
  a.bmin = fminf(a.bmin, b.bmin);   a.bmax = fmaxf(a.bmax, b.bmax);
}
__device__ inline void acc_wave_reduce(Acc8& a) {
  #pragma unroll
  for (int off = 32; off > 0; off >>= 1) {
    a.sum    += __shfl_down(a.sum, off);
    a.sumsq  += __shfl_down(a.sumsq, off);
    a.cnt    += __shfl_down(a.cnt, off);
    a.maxabs = fmaxf(a.maxabs, __shfl_down(a.maxabs, off));
    a.minnz  = fminf(a.minnz,  __shfl_down(a.minnz, off));
    a.maxnz  = fmaxf(a.maxnz,  __shfl_down(a.maxnz, off));
    a.bmin   = fminf(a.bmin,   __shfl_down(a.bmin, off));
    a.bmax   = fmaxf(a.bmax,   __shfl_down(a.bmax, off));
  }
}
template <int NWAVES>
__device__ inline bool acc_block_reduce(Acc8& a, Acc8* s_part) {
  __syncthreads();
  acc_wave_reduce(a);
  int tid = threadIdx.x;
  if ((tid & 63) == 0) s_part[tid >> 6] = a;
  __syncthreads();
  if (tid == 0) {
    #pragma unroll
    for (int w = 1; w < NWAVES; ++w) acc_merge(a, s_part[w]);
    return true;
  }
  return false;
}

// thr = mean + 3*sqrt(var), unbiased var over the masked (nonzero) set.
// Sum((a-m)^2) = sumsq - sum^2/n. fp64 internally, fp32 result (reference is fp32).
__device__ inline float compute_thr(double sum, double sumsq, unsigned n) {
  double nf = (double)(n > 0u ? n : 1u);
  double mean = sum / nf;
  double nm1 = nf - 1.0; if (nm1 < 1.0) nm1 = 1.0;
  double var = (sumsq - sum * sum / nf) / nm1;
  if (var < 0.0) var = 0.0;
  return (float)(mean + 3.0 * sqrt(var));
}

// delta/zp/valid for one group. special (thr > max_abs): inliers = remaining
// nonzero set (minnz/maxnz). Normal: inliers = band min/max, clamped with 0 for
// iters >= 1 (peeled zeros are inliers). delta==(xmax-xmin)/255.0f exact fp32
// division + rintf (half-even) to match jnp.round.
__device__ inline void finalize_group(float thr, float maxabs, unsigned n,
                                      float minnz, float maxnz, float bmin, float bmax,
                                      bool clampZero, float* dOut, float* zOut, int* vOut) {
  float xmin, xmax;
  if (thr > maxabs) { xmin = minnz; xmax = maxnz; }
  else {
    xmin = bmin; xmax = bmax;
    if (clampZero) { xmin = fminf(xmin, 0.0f); xmax = fmaxf(xmax, 0.0f); }
  }
  float d = (xmax - xmin) / 255.0f;
  int v = (n > 0u) ? 1 : 0;
  float z;
  if (v && d > 0.0f && d < BIGF) { z = rintf((-xmin) / d); }
  else { d = 1.0f; z = 0.0f; }   // invalid/degenerate slots: NaN-proof, never selected
  *dOut = d; *zOut = z; *vOut = v;
}

// ---------------------------------------------------------------------------
// K0: init
// ---------------------------------------------------------------------------
__global__ void k0_init(State* st) {
  if (threadIdx.x == 0 && blockIdx.x == 0) {
    st->sum0 = 0.0; st->sumsq0 = 0.0; st->n0 = 0u;
    st->maxabs0 = 0.0f; st->minnz0 = BIGF; st->maxnz0 = -BIGF;
    st->sum1 = 0.0; st->sumsq1 = 0.0; st->n1 = 0u;
    st->maxabs1 = 0.0f; st->minnz1 = BIGF; st->maxnz1 = -BIGF;
    st->sum2 = 0.0; st->sumsq2 = 0.0; st->n2 = 0u;
    st->maxabs2 = 0.0f; st->minnz2 = BIGF; st->maxnz2 = -BIGF;
    st->bmin0 = BIGF; st->bmax0 = -BIGF;
    st->bmin1 = BIGF; st->bmax1 = -BIGF;
    st->count1 = 0u; st->count2 = 0u;
  }
}

// ---------------------------------------------------------------------------
// K1: full-array stats over x != 0  (iteration-0 phase-1)
// ---------------------------------------------------------------------------
__global__ void __launch_bounds__(256) k1_stats(const float* __restrict__ x, long long n, State* st) {
  __shared__ Acc8 s_part[4];
  Acc8 a; acc_init(a);
  long long n4 = n >> 2;
  long long stride = (long long)gridDim.x * blockDim.x;
  const float4* x4 = (const float4*)x;
  for (long long i = (long long)blockIdx.x * blockDim.x + threadIdx.x; i < n4; i += stride) {
    float4 v = x4[i];
    float vv[4] = {v.x, v.y, v.z, v.w};
    #pragma unroll
    for (int k = 0; k < 4; ++k) {
      float f = vv[k];
      if (f != 0.0f) {
        float ab = fabsf(f);
        a.cnt++; a.sum += (double)ab; a.sumsq += (double)ab * (double)ab;
        a.maxabs = fmaxf(a.maxabs, ab);
        a.minnz = fminf(a.minnz, f); a.maxnz = fmaxf(a.maxnz, f);
      }
    }
  }
  for (long long i = (n4 << 2) + (long long)blockIdx.x * blockDim.x + threadIdx.x; i < n; i += stride) {
    float f = x[i];
    if (f != 0.0f) {
      float ab = fabsf(f);
      a.cnt++; a.sum += (double)ab; a.sumsq += (double)ab * (double)ab;
      a.maxabs = fmaxf(a.maxabs, ab);
      a.minnz = fminf(a.minnz, f); a.maxnz = fmaxf(a.maxnz, f);
    }
  }
  if (acc_block_reduce<4>(a, s_part)) {
    atomicAdd(&st->sum0, a.sum); atomicAdd(&st->sumsq0, a.sumsq); atomicAdd(&st->n0, a.cnt);
    atomicMaxF(&st->maxabs0, a.maxabs);
    atomicMinF(&st->minnz0, a.minnz); atomicMaxF(&st->maxnz0, a.maxnz);
  }
}

// ---------------------------------------------------------------------------
// K2: full pass with thr0: iter-0 inlier min/max, compact |x|>thr0, iter-1 stats
// ---------------------------------------------------------------------------
__global__ void __launch_bounds__(256) k2_pass(const float* __restrict__ x, long long n, State* st,
                                               float* __restrict__ buf1, unsigned cap1) {
  __shared__ Acc8 s_part[4];
  __shared__ float l_buf[LCAP];
  __shared__ unsigned l_cnt, l_base, l_m;
  if (threadIdx.x == 0) l_cnt = 0u;
  __syncthreads();

  float thr0 = compute_thr(st->sum0, st->sumsq0, st->n0);
  float maxabs0 = st->maxabs0;
  bool special = thr0 > maxabs0;   // then inliers = nonzero set (exclude zeros)

  Acc8 a; acc_init(a);
  long long n4 = n >> 2;
  long long stride = (long long)gridDim.x * blockDim.x;
  const float4* x4 = (const float4*)x;
  for (long long i = (long long)blockIdx.x * blockDim.x + threadIdx.x; i < n4; i += stride) {
    float4 v = x4[i];
    float vv[4] = {v.x, v.y, v.z, v.w};
    #pragma unroll
    for (int k = 0; k < 4; ++k) {
      float f = vv[k];
      float ab = fabsf(f);
      bool inl = special ? (f != 0.0f) : (ab <= thr0);
      if (inl) { a.bmin = fminf(a.bmin, f); a.bmax = fmaxf(a.bmax, f); }
      if (ab > thr0) {
        a.cnt++; a.sum += (double)ab; a.sumsq += (double)ab * (double)ab;
        a.maxabs = fmaxf(a.maxabs, ab);
        a.minnz = fminf(a.minnz, f); a.maxnz = fmaxf(a.maxnz, f);
        unsigned p = atomicAdd(&l_cnt, 1u);
        if (p < LCAP) l_buf[p] = f;
        else { unsigned g = atomicAdd(&st->count1, 1u); if (g < cap1) buf1[g] = f; }
      }
    }
  }
  for (long long i = (n4 << 2) + (long long)blockIdx.x * blockDim.x + threadIdx.x; i < n; i += stride) {
    float f = x[i];
    float ab = fabsf(f);
    bool inl = special ? (f != 0.0f) : (ab <= thr0);
    if (inl) { a.bmin = fminf(a.bmin, f); a.bmax = fmaxf(a.bmax, f); }
    if (ab > thr0) {
      a.cnt++; a.sum += (double)ab; a.sumsq += (double)ab * (double)ab;
      a.maxabs = fmaxf(a.maxabs, ab);
      a.minnz = fminf(a.minnz, f); a.maxnz = fmaxf(a.maxnz, f);
      unsigned p = atomicAdd(&l_cnt, 1u);
      if (p < LCAP) l_buf[p] = f;
      else { unsigned g = atomicAdd(&st->count1, 1u); if (g < cap1) buf1[g] = f; }
    }
  }
  // flush LDS-staged compaction with one global atomic per block
  __syncthreads();
  if (threadIdx.x == 0) {
    l_m = l_cnt < LCAP ? l_cnt : LCAP;
    l_base = atomicAdd(&st->count1, l_m);
  }
  __syncthreads();
  for (unsigned i = threadIdx.x; i < l_m; i += blockDim.x) {
    unsigned g = l_base + i;
    if (g < cap1) buf1[g] = l_buf[i];
  }
  if (acc_block_reduce<4>(a, s_part)) {
    atomicMinF(&st->bmin0, a.bmin); atomicMaxF(&st->bmax0, a.bmax);
    atomicAdd(&st->sum1, a.sum); atomicAdd(&st->sumsq1, a.sumsq); atomicAdd(&st->n1, a.cnt);
    atomicMaxF(&st->maxabs1, a.maxabs);
    atomicMinF(&st->minnz1, a.minnz); atomicMaxF(&st->maxnz1, a.maxnz);
  }
}

// ---------------------------------------------------------------------------
// K3: over compacted buf1 (~614K): iter-1 band min/max, compact |x|>thr1, iter-2 stats
// ---------------------------------------------------------------------------
__global__ void __launch_bounds__(256) k3_pass(State* st, const float* __restrict__ buf1, unsigned cap1,
                                               float* __restrict__ buf2, unsigned cap2) {
  __shared__ Acc8 s_part[4];
  __shared__ float l_buf[LCAP];
  __shared__ unsigned l_cnt, l_base, l_m;
  if (threadIdx.x == 0) l_cnt = 0u;
  __syncthreads();

  unsigned c1 = st->count1; if (c1 > cap1) c1 = cap1;
  float thr1 = compute_thr(st->sum1, st->sumsq1, st->n1);

  Acc8 a; acc_init(a);
  unsigned stride = gridDim.x * blockDim.x;
  for (unsigned j = blockIdx.x * blockDim.x + threadIdx.x; j < c1; j += stride) {
    float f = buf1[j];
    float ab = fabsf(f);
    if (ab <= thr1) { a.bmin = fminf(a.bmin, f); a.bmax = fmaxf(a.bmax, f); }
    else {
      a.cnt++; a.sum += (double)ab; a.sumsq += (double)ab * (double)ab;
      a.maxabs = fmaxf(a.maxabs, ab);
      a.minnz = fminf(a.minnz, f); a.maxnz = fmaxf(a.maxnz, f);
      unsigned p = atomicAdd(&l_cnt, 1u);
      if (p < LCAP) l_buf[p] = f;
      else { unsigned g = atomicAdd(&st->count2, 1u); if (g < cap2) buf2[g] = f; }
    }
  }
  __syncthreads();
  if (threadIdx.x == 0) {
    l_m = l_cnt < LCAP ? l_cnt : LCAP;
    l_base = atomicAdd(&st->count2, l_m);
  }
  __syncthreads();
  for (unsigned i = threadIdx.x; i < l_m; i += blockDim.x) {
    unsigned g = l_base + i;
    if (g < cap2) buf2[g] = l_buf[i];
  }
  if (acc_block_reduce<4>(a, s_part)) {
    atomicMinF(&st->bmin1, a.bmin); atomicMaxF(&st->bmax1, a.bmax);
    atomicAdd(&st->sum2, a.sum); atomicAdd(&st->sumsq2, a.sumsq); atomicAdd(&st->n2, a.cnt);
    atomicMaxF(&st->maxabs2, a.maxabs);
    atomicMinF(&st->minnz2, a.minnz); atomicMaxF(&st->maxnz2, a.maxnz);
  }
}

// ---------------------------------------------------------------------------
// K4: single block. Finalize groups 0,1; run iterations 2..9 over buf2 (~7K);
// emit thr/delta/zp/valid tables. Done-propagation: once n==0, stats stay 0
// (must NOT resurrect elements when thr resets to 0).
// ---------------------------------------------------------------------------
__global__ void __launch_bounds__(1024) k4_finalize(State* st, const float* __restrict__ buf2, unsigned cap2) {
  __shared__ Acc8 s_part[16];
  __shared__ float sh_thr[10], sh_delta[10], sh_zp[10];
  __shared__ int sh_valid[10];
  __shared__ double sh_sum, sh_sumsq;
  __shared__ unsigned sh_n;
  __shared__ float sh_maxabs, sh_minnz, sh_maxnz;
  int tid = threadIdx.x;

  if (tid == 0) {
    float thr0 = compute_thr(st->sum0, st->sumsq0, st->n0);
    sh_thr[0] = thr0;
    finalize_group(thr0, st->maxabs0, st->n0, st->minnz0, st->maxnz0,
                   st->bmin0, st->bmax0, /*clampZero=*/false,
                   &sh_delta[0], &sh_zp[0], &sh_valid[0]);
    float thr1 = compute_thr(st->sum1, st->sumsq1, st->n1);
    sh_thr[1] = thr1;
    finalize_group(thr1, st->maxabs1, st->n1, st->minnz1, st->maxnz1,
                   st->bmin1, st->bmax1, /*clampZero=*/true,
                   &sh_delta[1], &sh_zp[1], &sh_valid[1]);
    sh_sum = st->sum2; sh_sumsq = st->sumsq2; sh_n = st->n2;
    sh_maxabs = st->maxabs2; sh_minnz = st->minnz2; sh_maxnz = st->maxnz2;
  }
  __syncthreads();
  unsigned c2 = st->count2; if (c2 > cap2) c2 = cap2;

  for (int i = 2; i < 10; ++i) {
    if (tid == 0) sh_thr[i] = compute_thr(sh_sum, sh_sumsq, sh_n);
    __syncthreads();
    float tp = sh_thr[i - 1], tc = sh_thr[i];
    Acc8 a; acc_init(a);
    for (unsigned j = tid; j < c2; j += 1024u) {
      float f = buf2[j];
      float ab = fabsf(f);
      if (ab > tp && ab <= tc) { a.bmin = fminf(a.bmin, f); a.bmax = fmaxf(a.bmax, f); }
      if (ab > tc) {
        a.cnt++; a.sum += (double)ab; a.sumsq += (double)ab * (double)ab;
        a.maxabs = fmaxf(a.maxabs, ab);
        a.minnz = fminf(a.minnz, f); a.maxnz = fmaxf(a.maxnz, f);
      }
    }
    if (acc_block_reduce<16>(a, s_part)) {
      finalize_group(tc, sh_maxabs, sh_n, sh_minnz, sh_maxnz, a.bmin, a.bmax,
                     /*clampZero=*/true, &sh_delta[i], &sh_zp[i], &sh_valid[i]);
      if (sh_n > 0u) {  // done-propagation: keep zeros once dead
        sh_sum = a.sum; sh_sumsq = a.sumsq; sh_n = a.cnt;
        sh_maxabs = a.maxabs; sh_minnz = a.minnz; sh_maxnz = a.maxnz;
      }
    }
    __syncthreads();
  }
  if (tid < 10) {
    st->thr[tid] = sh_thr[tid]; st->delta[tid] = sh_delta[tid];
    st->zp[tid] = sh_zp[tid];   st->valid[tid] = sh_valid[tid];
  }
}

// ---------------------------------------------------------------------------
// K5: dequant. Tables in registers (fully unrolled -> cndmask select chain).
// gi-clip omitted: valids form a prefix, so any selected band i has i < n_groups.
// ---------------------------------------------------------------------------
__device__ inline float dq1(float v, const float* thr, const float* dl, const float* zp, const int* vld) {
  float ab = fabsf(v);
  float d = dl[0], z = zp[0];
  #pragma unroll
  for (int i = 1; i < 10; ++i) {
    bool band = (vld[i] != 0) && (ab > thr[i - 1]) && (ab <= thr[i]);
    d = band ? dl[i] : d;
    z = band ? zp[i] : z;
  }
  float q = rintf(v / d) + z;            // IEEE divide + half-even round, matches jnp
  q = fminf(fmaxf(q, 0.0f), 255.0f);
  return (q - z) * d;
}

__global__ void __launch_bounds__(256) k5_dequant(const float* __restrict__ x, float* __restrict__ out,
                                                  long long n, const State* __restrict__ st) {
  float thr[10], dl[10], zp[10]; int vld[10];
  #pragma unroll
  for (int i = 0; i < 10; ++i) {
    thr[i] = st->thr[i]; dl[i] = st->delta[i]; zp[i] = st->zp[i]; vld[i] = st->valid[i];
  }
  long long n4 = n >> 2;
  long long stride = (long long)gridDim.x * blockDim.x;
  const float4* x4 = (const float4*)x;
  float4* o4 = (float4*)out;
  for (long long i = (long long)blockIdx.x * blockDim.x + threadIdx.x; i < n4; i += stride) {
    float4 v = x4[i];
    float4 o;
    o.x = dq1(v.x, thr, dl, zp, vld);
    o.y = dq1(v.y, thr, dl, zp, vld);
    o.z = dq1(v.z, thr, dl, zp, vld);
    o.w = dq1(v.w, thr, dl, zp, vld);
    o4[i] = o;
  }
  for (long long i = (n4 << 2) + (long long)blockIdx.x * blockDim.x + threadIdx.x; i < n; i += stride) {
    out[i] = dq1(x[i], thr, dl, zp, vld);
  }
}

// ---------------------------------------------------------------------------
extern "C" void kernel_launch(void* const* d_in, const int* in_sizes, int n_in,
                              void* d_out, int out_size, void* d_ws, size_t ws_size,
                              hipStream_t stream) {
  const float* x = (const float*)d_in[0];
  float* out = (float*)d_out;
  long long n = (long long)in_sizes[0];

  State* st = (State*)d_ws;
  const size_t state_sz = 4096;
  size_t avail = ws_size > state_sz ? ws_size - state_sz : 0;
  // buf2 gets 1/8 of remaining (cap 1M elems), buf1 the rest.
  size_t cap2_sz = avail / 8;
  if (cap2_sz > (size_t)(1u << 20) * 4) cap2_sz = (size_t)(1u << 20) * 4;
  unsigned cap2 = (unsigned)(cap2_sz / 4);
  float* buf2 = (float*)((char*)d_ws + state_sz);
  float* buf1 = buf2 + cap2;
  unsigned cap1 = (unsigned)((avail - (size_t)cap2 * 4) / 4);

  hipLaunchKernelGGL(k0_init, dim3(1), dim3(64), 0, stream, st);
  hipLaunchKernelGGL(k1_stats, dim3(4096), dim3(256), 0, stream, x, n, st);
  hipLaunchKernelGGL(k2_pass, dim3(4096), dim3(256), 0, stream, x, n, st, buf1, cap1);
  hipLaunchKernelGGL(k3_pass, dim3(256), dim3(256), 0, stream, st, buf1, cap1, buf2, cap2);
  hipLaunchKernelGGL(k4_finalize, dim3(1), dim3(1024), 0, stream, st, buf2, cap2);
  hipLaunchKernelGGL(k5_dequant, dim3(4096), dim3(256), 0, stream, x, out, n, st);
}